// Round 8
// baseline (261.235 us; speedup 1.0000x reference)
//
#include <hip/hip_runtime.h>

#define ZC     256
#define KCODES 1024
#define MARGIN 1e-4f

typedef __attribute__((ext_vector_type(4))) float f32x4;
typedef __attribute__((ext_vector_type(8))) short s16x8;
typedef unsigned int u32t;
typedef u32t __attribute__((address_space(1))) as1_u32;
typedef u32t __attribute__((address_space(3))) as3_u32;

__device__ __forceinline__ void glds16(const void* g, void* l) {
    __builtin_amdgcn_global_load_lds((const as1_u32*)g, (as3_u32*)l, 16, 0, 0);
}
__device__ __forceinline__ unsigned short bf16_rn(float x) {
    union { float f; u32t u; } v; v.f = x;
    return (unsigned short)((v.u + 0x7FFFu + ((v.u >> 16) & 1u)) >> 16);
}
__device__ __forceinline__ float bf16_f(unsigned short h) {
    union { u32t u; float f; } v; v.u = ((u32t)h) << 16; return v.f;
}

// ---------------------------------------------------------------------------
// prep_z: z fp32 [32,256,32,32] -> A' bf16 [8 kblk][32768 pt][64 k], swizzle
// baked in global layout: short col = k ^ ((pt&7)<<3). (verified round 7)
// ---------------------------------------------------------------------------
__global__ __launch_bounds__(256)
void vq_prep_z(const float* __restrict__ z, unsigned short* __restrict__ Ab)
{
    const int t = threadIdx.x, blk = blockIdx.x;
    const int pt = (blk >> 3) * 64 + (t & 63);
    const int c0 = (blk & 7) * 32 + (t >> 6) * 8;
    const int b = pt >> 10, hw = pt & 1023;
    const float* zp = z + (size_t)b * (ZC * 1024) + (size_t)c0 * 1024 + hw;

    unsigned short hi[8], lo[8];
    #pragma unroll
    for (int j = 0; j < 8; ++j) {
        const float v = zp[(size_t)j * 1024];
        const unsigned short h = bf16_rn(v);
        hi[j] = h; lo[j] = bf16_rn(v - bf16_f(h));
    }
    uint4 ph, pl;
    ph.x = (u32t)hi[0] | ((u32t)hi[1] << 16); ph.y = (u32t)hi[2] | ((u32t)hi[3] << 16);
    ph.z = (u32t)hi[4] | ((u32t)hi[5] << 16); ph.w = (u32t)hi[6] | ((u32t)hi[7] << 16);
    pl.x = (u32t)lo[0] | ((u32t)lo[1] << 16); pl.y = (u32t)lo[2] | ((u32t)lo[3] << 16);
    pl.z = (u32t)lo[4] | ((u32t)lo[5] << 16); pl.w = (u32t)lo[6] | ((u32t)lo[7] << 16);

    const size_t kbH = (size_t)(c0 >> 6), kbL = kbH + 4;
    const int sw = (c0 & 63) ^ ((pt & 7) << 3);
    const size_t base = (size_t)pt * 64 + sw;
    *reinterpret_cast<uint4*>(Ab + kbH * (32768ull * 64) + base) = ph;
    *reinterpret_cast<uint4*>(Ab + kbL * (32768ull * 64) + base) = pl;
}

// ---------------------------------------------------------------------------
// prep_e: emb fp32 [1024,256] -> B' bf16 [8 kblk][1024 code][64], same swizzle.
// ---------------------------------------------------------------------------
__global__ __launch_bounds__(256)
void vq_prep_e(const float* __restrict__ emb, unsigned short* __restrict__ Bb)
{
    const int t = threadIdx.x, blk = blockIdx.x;
    const int code = (blk >> 3) * 64 + (t & 63);
    const int c0 = (blk & 7) * 32 + (t >> 6) * 8;
    const float* ep = emb + (size_t)code * ZC + c0;

    unsigned short hi[8], lo[8];
    #pragma unroll
    for (int j = 0; j < 8; ++j) {
        const float v = ep[j];
        const unsigned short h = bf16_rn(v);
        hi[j] = h; lo[j] = bf16_rn(v - bf16_f(h));
    }
    uint4 ph, pl;
    ph.x = (u32t)hi[0] | ((u32t)hi[1] << 16); ph.y = (u32t)hi[2] | ((u32t)hi[3] << 16);
    ph.z = (u32t)hi[4] | ((u32t)hi[5] << 16); ph.w = (u32t)hi[6] | ((u32t)hi[7] << 16);
    pl.x = (u32t)lo[0] | ((u32t)lo[1] << 16); pl.y = (u32t)lo[2] | ((u32t)lo[3] << 16);
    pl.z = (u32t)lo[4] | ((u32t)lo[5] << 16); pl.w = (u32t)lo[6] | ((u32t)lo[7] << 16);

    const size_t kbH = (size_t)(c0 >> 6), kbL = kbH + 4;
    const int sw = (c0 & 63) ^ ((code & 7) << 3);
    const size_t base = (size_t)code * 64 + sw;
    *reinterpret_cast<uint4*>(Bb + kbH * (1024ull * 64) + base) = ph;
    *reinterpret_cast<uint4*>(Bb + kbL * (1024ull * 64) + base) = pl;
}

// ---------------------------------------------------------------------------
// ens: codebook squared norms -> ens_g[1024]; zeroes fixup counter.
// ---------------------------------------------------------------------------
__global__ __launch_bounds__(256)
void vq_ens(const float* __restrict__ emb, float* __restrict__ ens_g,
            int* __restrict__ cnt)
{
    if (blockIdx.x == 0 && threadIdx.x == 0) *cnt = 0;
    const int t = threadIdx.x, lane = t & 63, w = t >> 6;
    for (int rep = 0; rep < 16; ++rep) {
        const int k = blockIdx.x * 64 + rep * 4 + w;
        const float4 v = *reinterpret_cast<const float4*>(emb + (size_t)k * ZC + lane * 4);
        float s = v.x * v.x + v.y * v.y + v.z * v.z + v.w * v.w;
        #pragma unroll
        for (int m = 1; m < 64; m <<= 1) s += __shfl_xor(s, m);
        if (lane == 0) ens_g[k] = s;
    }
}

// ---------------------------------------------------------------------------
// GEMM+argmin: 4 waves, tile 64 pts x 256 codes/ct (4 cts), 12 k-steps x 64.
// Per wave: 4 m-frags x 4 n-frags (32 MFMA per k-step, 16 ds_read_b128).
// 2-phase double-buffered glds staging: issue next tile BEFORE computing
// current, single barrier per k-step. Reduction/merge verified rounds 5-7.
// ---------------------------------------------------------------------------
__global__ __launch_bounds__(256, 2)
void vq_gemm_argmin(const unsigned short* __restrict__ Ab,
                    const unsigned short* __restrict__ Bb,
                    const float* __restrict__ ens_g, float* __restrict__ out_idx)
{
    __shared__ unsigned short As[2][4096];    // 2 x 8 KB (64 rows x 64)
    __shared__ unsigned short Bs[2][16384];   // 2 x 32 KB (256 rows x 64)

    const int t = threadIdx.x;
    const int lane = t & 63, wv = t >> 6;
    const int col = lane & 15, kg = lane >> 4;
    const int pt0 = blockIdx.x * 64;
    const int kx = (col & 7) << 3;            // read-side XOR (shorts)

    int aoff[4][2], boff[4][2];               // offsets in shorts
    #pragma unroll
    for (int m = 0; m < 4; ++m)
        #pragma unroll
        for (int s = 0; s < 2; ++s)
            aoff[m][s] = (m * 16 + col) * 64 + ((s * 32 + kg * 8) ^ kx);
    #pragma unroll
    for (int n = 0; n < 4; ++n)
        #pragma unroll
        for (int s = 0; s < 2; ++s)
            boff[n][s] = (wv * 64 + n * 16 + col) * 64 + ((s * 32 + kg * 8) ^ kx);

    f32x4 acc[4][4];
    #pragma unroll
    for (int m = 0; m < 4; ++m)
        #pragma unroll
        for (int n = 0; n < 4; ++n) acc[m][n] = (f32x4){0.f, 0.f, 0.f, 0.f};

    float v1[16], v2[16]; int id1[16];
    #pragma unroll
    for (int i = 0; i < 16; ++i) { v1[i] = 3.4e38f; v2[i] = 3.4e38f; id1[i] = 0; }

    auto STAGE = [&](int buf, int ctn, int ksn) {
        const int kbA = (((ksn >> 2) == 1) ? 4 : 0) + (ksn & 3);
        const int kbB = (((ksn >> 2) == 2) ? 4 : 0) + (ksn & 3);
        const char* aS = (const char*)(Ab + (size_t)kbA * 2097152ull + (size_t)pt0 * 64);
        const char* bS = (const char*)(Bb + (size_t)kbB * 65536ull + (size_t)ctn * 16384);
        char* aD = (char*)&As[buf][0];
        char* bD = (char*)&Bs[buf][0];
        glds16(aS + t * 16,        aD + t * 16);
        glds16(aS + 4096 + t * 16, aD + 4096 + t * 16);
        #pragma unroll
        for (int q = 0; q < 8; ++q)
            glds16(bS + q * 4096 + t * 16, bD + q * 4096 + t * 16);
    };

    STAGE(0, 0, 0);
    __syncthreads();     // drains prologue stage

    int cur = 0;
    for (int ct = 0; ct < 4; ++ct) {
        for (int ks = 0; ks < 12; ++ks) {
            // issue next-tile stage FIRST (hides under compute below)
            if (!(ct == 3 && ks == 11)) {
                const int ctn = (ks == 11) ? ct + 1 : ct;
                const int ksn = (ks == 11) ? 0 : ks + 1;
                STAGE(cur ^ 1, ctn, ksn);
            }
            // compute current buffer
            const unsigned short* ab = &As[cur][0];
            const unsigned short* bb = &Bs[cur][0];
            s16x8 af[4][2], bf[4][2];
            #pragma unroll
            for (int m = 0; m < 4; ++m)
                #pragma unroll
                for (int s = 0; s < 2; ++s)
                    af[m][s] = *reinterpret_cast<const s16x8*>(ab + aoff[m][s]);
            #pragma unroll
            for (int n = 0; n < 4; ++n)
                #pragma unroll
                for (int s = 0; s < 2; ++s)
                    bf[n][s] = *reinterpret_cast<const s16x8*>(bb + boff[n][s]);
            #pragma unroll
            for (int m = 0; m < 4; ++m)
                #pragma unroll
                for (int n = 0; n < 4; ++n) {
                    acc[m][n] = __builtin_amdgcn_mfma_f32_16x16x32_bf16(af[m][0], bf[n][0], acc[m][n], 0, 0, 0);
                    acc[m][n] = __builtin_amdgcn_mfma_f32_16x16x32_bf16(af[m][1], bf[n][1], acc[m][n], 0, 0, 0);
                }

            if (ks == 11) {   // code-tile epilogue: top-2 update, reset acc
                #pragma unroll
                for (int n = 0; n < 4; ++n) {
                    const int code = ct * 256 + wv * 64 + n * 16 + col;
                    const float en = ens_g[code];
                    #pragma unroll
                    for (int m = 0; m < 4; ++m)
                        #pragma unroll
                        for (int j = 0; j < 4; ++j) {
                            const float sc = fmaf(-2.f, acc[m][n][j], en);
                            const int sl = m * 4 + j;
                            if (sc < v1[sl]) { v2[sl] = v1[sl]; v1[sl] = sc; id1[sl] = code; }
                            else if (sc < v2[sl]) { v2[sl] = sc; }
                            acc[m][n][j] = 0.f;
                        }
                }
            }
            __syncthreads();   // one barrier per k-step (drains stage + LDS reads)
            cur ^= 1;
        }
    }

    // in-wave 16-lane top-2 merge (verified rounds 5-7)
    float w1[16], w2[16]; int wid[16];
    #pragma unroll
    for (int sl = 0; sl < 16; ++sl) {
        float a1 = v1[sl]; int ai = id1[sl]; float a2 = v2[sl];
        #pragma unroll
        for (int mk = 1; mk < 16; mk <<= 1) {
            const float o1 = __shfl_xor(a1, mk);
            const int   oi = __shfl_xor(ai, mk);
            const float o2 = __shfl_xor(a2, mk);
            if (o1 < a1)      { a2 = fminf(a1, o2); a1 = o1; ai = oi; }
            else if (o1 > a1) { a2 = fminf(a2, o1); }
            else              { a2 = (oi != ai) ? a1 : fminf(a2, o2); ai = (oi < ai) ? oi : ai; }
        }
        w1[sl] = a1; w2[sl] = a2; wid[sl] = ai;
    }

    // cross-wave merge via LDS (verified rounds 5-7)
    __syncthreads();
    float* mv1 = reinterpret_cast<float*>(&As[0][0]);
    float* mv2 = mv1 + 256;
    int*   mid = reinterpret_cast<int*>(mv2 + 256);
    if (col == 0) {
        #pragma unroll
        for (int sl = 0; sl < 16; ++sl) {
            const int m = sl >> 2, j = sl & 3;
            const int p = m * 16 + kg * 4 + j;
            mv1[wv * 64 + p] = w1[sl];
            mv2[wv * 64 + p] = w2[sl];
            mid[wv * 64 + p] = wid[sl];
        }
    }
    __syncthreads();
    if (t < 64) {
        float a1 = mv1[t], a2 = mv2[t]; int ai = mid[t];
        #pragma unroll
        for (int w = 1; w < 4; ++w) {
            const float b1 = mv1[w * 64 + t], b2 = mv2[w * 64 + t];
            const int   bi = mid[w * 64 + t];
            if (b1 < a1)      { a2 = fminf(a1, b2); a1 = b1; ai = bi; }
            else if (b1 > a1) { a2 = fminf(a2, b1); }
            else              { a2 = a1; ai = (bi < ai) ? bi : ai; }
        }
        out_idx[pt0 + t] = ((a2 - a1) <= MARGIN) ? (-1.0f - (float)ai) : (float)ai;
    }
}

// ---------------------------------------------------------------------------
// compact: flagged points -> worklist.
// ---------------------------------------------------------------------------
__global__ __launch_bounds__(256)
void vq_compact(const float* __restrict__ idxf, int* __restrict__ cnt,
                int* __restrict__ list)
{
    const int n = blockIdx.x * 256 + threadIdx.x;
    if (idxf[n] < 0.f) { const int p = atomicAdd(cnt, 1); list[p] = n; }
}

// ---------------------------------------------------------------------------
// numpy pairwise-sum replication (verified round 2).
// ---------------------------------------------------------------------------
__device__ __forceinline__ float np_pair128_sq(const float* __restrict__ a) {
    float r[8];
    #pragma unroll
    for (int j = 0; j < 8; ++j) r[j] = __fmul_rn(a[j], a[j]);
    #pragma unroll
    for (int i = 8; i < 128; i += 8)
        #pragma unroll
        for (int j = 0; j < 8; ++j) r[j] = __fadd_rn(r[j], __fmul_rn(a[i + j], a[i + j]));
    const float s01 = __fadd_rn(r[0], r[1]);
    const float s23 = __fadd_rn(r[2], r[3]);
    const float s45 = __fadd_rn(r[4], r[5]);
    const float s67 = __fadd_rn(r[6], r[7]);
    return __fadd_rn(__fadd_rn(s01, s23), __fadd_rn(s45, s67));
}
__device__ __forceinline__ float np_sum256_sq(const float* __restrict__ a) {
    return __fadd_rn(np_pair128_sq(a), np_pair128_sq(a + 128));
}

// ---------------------------------------------------------------------------
// fixup2 (verified round 6): one block per flagged point, np-exact adjudication.
// ---------------------------------------------------------------------------
__global__ __launch_bounds__(256)
void vq_fixup2(const float* __restrict__ z, const float* __restrict__ emb,
               float* __restrict__ idxf, const int* __restrict__ cnt,
               const int* __restrict__ list)
{
    __shared__ float zs[ZC];
    __shared__ float es[32 * 264];
    __shared__ float gbv[32];
    __shared__ int   gbk[32];

    const int t = threadIdx.x;
    const int g = t >> 3, r = t & 7;
    const int C = *cnt;

    for (int it = blockIdx.x; it < C; it += 512) {
        const int n = list[it];
        const int b = n >> 10, q = n & 1023;
        __syncthreads();
        zs[t] = z[(size_t)b * (ZC * 1024) + (size_t)t * 1024 + q];
        __syncthreads();

        const float zn = np_sum256_sq(zs);

        float best = 3.4e38f; int bestk = 0x7fffffff;

        for (int tile = 0; tile < 32; ++tile) {
            __syncthreads();
            const float4* src = reinterpret_cast<const float4*>(emb + (size_t)tile * 32 * ZC);
            #pragma unroll
            for (int i = 0; i < 8; ++i) {
                const int f = i * 256 + t;
                const int row = f >> 6, c4 = f & 63;
                *reinterpret_cast<float4*>(es + row * 264 + c4 * 4) = src[f];
            }
            __syncthreads();

            const float* er = es + g * 264;
            float lo, hi;
            double dd;
            {
                const float a0 = er[r];
                const float a1 = er[128 + r];
                lo = __fmul_rn(a0, a0);
                hi = __fmul_rn(a1, a1);
                dd = fma((double)a0, (double)zs[r],
                     fma((double)a1, (double)zs[128 + r], 0.0));
            }
            #pragma unroll
            for (int i = 1; i < 16; ++i) {
                const int c = 8 * i + r;
                const float a0 = er[c];
                const float a1 = er[128 + c];
                lo = __fadd_rn(lo, __fmul_rn(a0, a0));
                hi = __fadd_rn(hi, __fmul_rn(a1, a1));
                dd = fma((double)a0, (double)zs[c], dd);
                dd = fma((double)a1, (double)zs[128 + c], dd);
            }
            #pragma unroll
            for (int mk = 1; mk < 8; mk <<= 1) {
                lo = __fadd_rn(lo, __shfl_xor(lo, mk));
                hi = __fadd_rn(hi, __shfl_xor(hi, mk));
                dd = dd + __shfl_xor(dd, mk);
            }
            if (r == 0) {
                const float en  = __fadd_rn(lo, hi);
                const float t2f = (float)dd;
                const float d   = __fsub_rn(__fadd_rn(zn, en), __fmul_rn(2.0f, t2f));
                const int code  = tile * 32 + g;
                if (d < best) { best = d; bestk = code; }
            }
        }

        if (r == 0) { gbv[g] = best; gbk[g] = bestk; }
        __syncthreads();
        if (t == 0) {
            float bv = gbv[0]; int bk = gbk[0];
            for (int gg = 1; gg < 32; ++gg)
                if (gbv[gg] < bv || (gbv[gg] == bv && gbk[gg] < bk)) { bv = gbv[gg]; bk = gbk[gg]; }
            idxf[n] = (float)bk;
        }
        __syncthreads();
    }
}

// ---------------------------------------------------------------------------
// outputs (verified round 2) — overwrites the scratch regions.
// ---------------------------------------------------------------------------
__global__ __launch_bounds__(256)
void vq_outputs_kernel(const float* __restrict__ z, const float* __restrict__ emb,
                       const float* __restrict__ idxf,
                       float* __restrict__ out_q, float* __restrict__ out_loss)
{
    __shared__ float zts[32 * 257];
    __shared__ int   ids[32];

    const int t  = threadIdx.x;
    const int bh = blockIdx.x;
    const int b  = bh >> 5, h = bh & 31;
    const int n0 = bh * 32;

    if (t < 32) ids[t] = (int)idxf[n0 + t];
    __syncthreads();

    const size_t zbase = (size_t)b * (ZC * 1024) + h * 32;

    for (int rep = 0; rep < 32; ++rep) {
        const int flat = rep * 256 + t;
        const int c = flat >> 5;
        const int ww = flat & 31;
        const size_t ga = zbase + (size_t)c * 1024 + ww;
        const float zv = z[ga];
        zts[ww * 257 + c] = zv;
        out_q[ga] = emb[(size_t)ids[ww] * ZC + c];
    }
    __syncthreads();

    for (int rep = 0; rep < 32; ++rep) {
        const float e = emb[(size_t)ids[rep] * ZC + t];
        const float d = e - zts[rep * 257 + t];
        out_loss[(size_t)(n0 + rep) * ZC + t] = 1.25f * d * d;
    }
}

extern "C" void kernel_launch(void* const* d_in, const int* in_sizes, int n_in,
                              void* d_out, int out_size, void* d_ws, size_t ws_size,
                              hipStream_t stream)
{
    const float* z   = (const float*)d_in[0];   // [32,256,32,32]
    const float* emb = (const float*)d_in[1];   // [1024,256]
    float* out      = (float*)d_out;
    float* out_q    = out;                       // 8388608 floats
    float* out_loss = out + 8388608;             // 8388608 floats
    float* out_idx  = out + 16777216;            // 32768 floats

    // scratch carved from output regions (fully overwritten by final kernels):
    unsigned short* Ab = (unsigned short*)d_out;                       // 32 MiB (out_q)
    unsigned short* Bb = (unsigned short*)((char*)d_out + 33554432);   // 1 MiB
    float* ensg = (float*)((char*)d_out + 34603008);                   // 4 KiB
    int*   cnt  = (int*)  ((char*)d_out + 34607104);                   // 4 B
    int*   list = (int*)  ((char*)d_out + 34607168);                   // 128 KiB max

    vq_prep_z        <<<4096, 256, 0, stream>>>(z, Ab);
    vq_prep_e        <<<128,  256, 0, stream>>>(emb, Bb);
    vq_ens           <<<16,   256, 0, stream>>>(emb, ensg, cnt);
    vq_gemm_argmin   <<<512,  256, 0, stream>>>(Ab, Bb, ensg, out_idx);
    vq_compact       <<<128,  256, 0, stream>>>(out_idx, cnt, list);
    vq_fixup2        <<<512,  256, 0, stream>>>(z, emb, out_idx, cnt, list);
    vq_outputs_kernel<<<1024, 256, 0, stream>>>(z, emb, out_idx, out_q, out_loss);
}